// Round 7
// baseline (149.008 us; speedup 1.0000x reference)
//
#include <hip/hip_runtime.h>

typedef _Float16 half8 __attribute__((ext_vector_type(8)));
typedef _Float16 half4 __attribute__((ext_vector_type(4)));
typedef __fp16   fp16x2 __attribute__((ext_vector_type(2)));
typedef float f32x4  __attribute__((ext_vector_type(4)));

#define DEVI __device__ __forceinline__

// problem constants (B,H,W,C fixed by the reference)
constexpr int Bc = 8;
constexpr int Hc = 224;
constexpr int Wc = 224;
constexpr int Cc = 256;
constexpr int NQ = 64;
constexpr int TS = 32;        // cell tile side (224/7)
constexpr int Lc = TS * TS;   // 1024 positions per cell
constexpr int KL = 32;        // l-chunk = ONE image row of the tile
constexpr int NT = Lc / KL;   // 32 chunks per full cell

// split-L partial layout in d_ws: per (cell,half):
//   [64][256] fp16 O~ (unnormalized, rel. local max)  = 32768 B
//   [64] f32 m                                        =   256 B
//   [64] f32 l                                        =   256 B
constexpr long PSTRIDE = 64 * 256 * 2 + 64 * 4 + 64 * 4;   // 33280
constexpr long WS_NEED = 784 * PSTRIDE;                    // ~26.1 MB

// fp16-element index inside a 32x256 chunk, subtiled [l/4][c/16][4][16]
DEVI int subidx(int l, int c) {
  return ((((l >> 2) << 4) | (c >> 4)) << 6) | (((l & 3) << 4) | (c & 15));
}

// LDS byte offset of a shared-memory pointer (generic -> AS(3) addrspacecast)
DEVI uint ldsoff(const void* p) {
  return (uint)(uintptr_t)(const __attribute__((address_space(3))) char*)p;
}

union PKU { fp16x2 h; uint u; };
DEVI uint pkrtz(float a, float b) { PKU x; x.h = __builtin_amdgcn_cvt_pkrtz(a, b); return x.u; }
union HBU { _Float16 h; ushort u; };
DEVI ushort hbits(float x) { HBU v; v.h = (_Float16)x; return v.u; }

__global__ __launch_bounds__(256, 3) void attn_cells(
    const float* __restrict__ img,   // fp32 [B,224,224,256]
    const float* __restrict__ qry,   // fp32 [64,256]
    float* __restrict__ out,         // fp32 [B,49,64,256]   (splt==0)
    char* __restrict__ wsp,          // partials             (splt==1)
    int splt)
{
  __shared__ _Float16 Rlds[2][KL * Cc]; // 2 x 16KB, subtiled fp16
  __shared__ _Float16 Plds[4][16 * 64]; // per-wave P rows (128B stride), swizzled
  __shared__ float    Slds[NQ];         // per-chunk rescale factors
  __shared__ float    Llds[NQ];         // final sum-exp

  const int tid  = threadIdx.x;
  const int w    = tid >> 6;          // wave 0..3
  const int lane = tid & 63;
  const int lp   = lane & 15;
  const int gq   = lane >> 4;         // 0..3

  const int bx = blockIdx.x;
  const int bn = splt ? (bx >> 1) : bx;   // cell id: b*49 + (i*7+j)
  const int h  = splt ? (bx & 1)  : 0;    // L-half
  const int tbeg = h * 16;
  const int tend = tbeg + (splt ? 16 : NT);

  const int b  = bn / 49;
  const int n  = bn % 49;
  const int i0 = n / 7, j0 = n % 7;

  const long cellbase = (((long)b * Hc + i0 * TS) * Wc + j0 * TS) * Cc;

  // staging decode: 4 granules of 8 elements per thread; granule G covers
  // chunk elements [8G, 8G+8) == R[l][c..c+7] in the subtiled layout.
  // chunk t == image row t of the tile: gaddr = chunkbase + l*Cc + c.
  int goff[4], lds_off[4];
  #pragma unroll
  for (int s = 0; s < 4; ++s) {
    int G   = s * 256 + tid;                       // 0..1023
    int blk = G >> 3, sub = G & 7;
    int l   = ((blk >> 4) << 2) | ((sub >> 1) & 3);
    int c   = ((blk & 15) << 4) | ((sub & 1) << 3);
    goff[s]    = l * Cc + c;                       // + t*Wc*Cc per chunk
    lds_off[s] = G << 3;                           // fp16 elements
  }

  // Q fragments (B-operand of S^T = R.Q^T), RNE convert (one-time)
  half8 bq[8];
  {
    const int qrow = (w << 4) | lp;
    #pragma unroll
    for (int kc = 0; kc < 8; ++kc) {
      const float* qp = &qry[qrow * Cc + kc * 32 + gq * 8];
      f32x4 lo = *(const f32x4*)qp;
      f32x4 hi = *(const f32x4*)(qp + 4);
      half8 hh;
      #pragma unroll
      for (int j = 0; j < 4; ++j) { hh[j] = (_Float16)lo[j]; hh[j + 4] = (_Float16)hi[j]; }
      bq[kc] = hh;
    }
  }

  f32x4 acc[4][4];
  #pragma unroll
  for (int qb = 0; qb < 4; ++qb)
    #pragma unroll
    for (int cb = 0; cb < 4; ++cb) acc[qb][cb] = f32x4{0.f, 0.f, 0.f, 0.f};

  float mrun = -3.0e38f;
  float lsum = 0.0f;

  // prologue: stage chunk tbeg (tbeg even -> buffer 0)
  {
    const float* gb = img + cellbase + (long)tbeg * (Wc * Cc);
    #pragma unroll
    for (int s = 0; s < 4; ++s) {
      f32x4 lo = *(const f32x4*)&gb[goff[s]];
      f32x4 hi = *(const f32x4*)&gb[goff[s] + 4];
      uint4 pk;
      pk.x = pkrtz(lo[0], lo[1]); pk.y = pkrtz(lo[2], lo[3]);
      pk.z = pkrtz(hi[0], hi[1]); pk.w = pkrtz(hi[2], hi[3]);
      *(uint4*)&Rlds[0][lds_off[s]] = pk;
    }
  }
  __syncthreads();

  // per-lane base for PV tr-reads: lane (gq,lp) reads 4 contiguous fp16 at
  // R[l0 + (lp>>2)][c0 + 4*(lp&3)]; HW permutation delivers
  // out[j] = R[l0+j][c0+lp].  l0 = gq*8+u*4, c0 = w*64+cb*16.
  const uint trlane = (uint)(gq * 4096 + w * 512 +
                             ((((lp >> 2) << 4) | ((lp & 3) << 2)) << 1));

  for (int t = tbeg; t < tend; ++t) {
    const int pb = t & 1;
    const _Float16* Rbuf = &Rlds[pb][0];
    const uint trbase = ldsoff(Rbuf) + trlane;

    if (t + 1 < tend) {   // stage next chunk into the free buffer
      const float* gb = img + cellbase + (long)(t + 1) * (Wc * Cc);
      _Float16* Rn = &Rlds[pb ^ 1][0];
      #pragma unroll
      for (int s = 0; s < 4; ++s) {
        f32x4 lo = *(const f32x4*)&gb[goff[s]];
        f32x4 hi = *(const f32x4*)&gb[goff[s] + 4];
        uint4 pk;
        pk.x = pkrtz(lo[0], lo[1]); pk.y = pkrtz(lo[2], lo[3]);
        pk.z = pkrtz(hi[0], hi[1]); pk.w = pkrtz(hi[2], hi[3]);
        *(uint4*)&Rn[lds_off[s]] = pk;
      }
    }

    // ---- S^T = R . Q^T  (wave handles q rows 16w..16w+15) ----
    f32x4 sv[2];
    #pragma unroll
    for (int lb = 0; lb < 2; ++lb) sv[lb] = f32x4{0.f, 0.f, 0.f, 0.f};
    #pragma unroll
    for (int kc = 0; kc < 8; ++kc) {
      #pragma unroll
      for (int lb = 0; lb < 2; ++lb) {
        half8 a = *(const half8*)&Rbuf[subidx(lb * 16 + lp, kc * 32 + gq * 8)];
        sv[lb] = __builtin_amdgcn_mfma_f32_16x16x32_f16(a, bq[kc], sv[lb], 0, 0, 0);
      }
    }
    // lane holds S^T[l = 16lb+4gq+r][q = 16w+lp]

    // ---- online softmax for q = 16w+lp ----
    float cmax = sv[0][0];
    #pragma unroll
    for (int lb = 0; lb < 2; ++lb)
      #pragma unroll
      for (int r = 0; r < 4; ++r) cmax = fmaxf(cmax, sv[lb][r]);
    cmax = fmaxf(cmax, __shfl_xor(cmax, 16));
    cmax = fmaxf(cmax, __shfl_xor(cmax, 32));

    float mnew  = fmaxf(mrun, cmax);
    float scale = __expf(mrun - mnew);

    // fused: exp + pack + LDS write + partial sum
    float ps = 0.0f;
    {
      char* Pw = (char*)&Plds[w][0];
      #pragma unroll
      for (int lb = 0; lb < 2; ++lb) {
        float p0 = __expf(sv[lb][0] - mnew);
        float p1 = __expf(sv[lb][1] - mnew);
        float p2 = __expf(sv[lb][2] - mnew);
        float p3 = __expf(sv[lb][3] - mnew);
        ps += (p0 + p1) + (p2 + p3);
        int base = lp * 128 + lb * 32 + gq * 8;   // byte of P[lp][l=16lb+4gq]
        int swz  = (lp & 7) << 4;
        *(uint*)(Pw + ((base ^ swz)))     = pkrtz(p0, p1);
        *(uint*)(Pw + ((base ^ swz) + 4)) = pkrtz(p2, p3);
      }
      if (lane < 16) Slds[w * 16 + lp] = scale;
    }
    ps += __shfl_xor(ps, 16);
    ps += __shfl_xor(ps, 32);
    lsum = lsum * scale + ps;
    mrun = mnew;

    __syncthreads();   // P + scale visible to all waves

    // ---- PV: wave computes O[all 64 q][c slice 64w..64w+64) ----
    #pragma unroll
    for (int qb = 0; qb < 4; ++qb) {
      f32x4 sc = *(const f32x4*)&Slds[qb * 16 + gq * 4];
      #pragma unroll
      for (int cb = 0; cb < 4; ++cb) acc[qb][cb] *= sc;
    }

    {
      half8 pa[4];
      #pragma unroll
      for (int qb = 0; qb < 4; ++qb) {
        const char* Pr = (const char*)&Plds[qb][0];
        int off = (lp * 128 + gq * 16) ^ ((lp & 7) << 4);
        pa[qb] = *(const half8*)(Pr + off);
      }
      // PV B-frags via hardware transpose read (T10)
      half4 tr[4][2];
      #pragma unroll
      for (int cb = 0; cb < 4; ++cb) {
        #pragma unroll
        for (int u = 0; u < 2; ++u) {
          asm volatile("ds_read_b64_tr_b16 %0, %1 offset:%2"
                       : "=v"(tr[cb][u])
                       : "v"(trbase), "i"(u * 2048 + cb * 128));
        }
      }
      asm volatile("s_waitcnt lgkmcnt(0)" ::: "memory");
      __builtin_amdgcn_sched_barrier(0);

      #pragma unroll
      for (int qb = 0; qb < 4; ++qb)
        #pragma unroll
        for (int cb = 0; cb < 4; ++cb) {
          half8 bv = __builtin_shufflevector(tr[cb][0], tr[cb][1], 0, 1, 2, 3, 4, 5, 6, 7);
          acc[qb][cb] = __builtin_amdgcn_mfma_f32_16x16x32_f16(pa[qb], bv, acc[qb][cb], 0, 0, 0);
        }
    }

    __syncthreads();   // frees R buffer and P region
  }

  // ---- epilogue ----
  if (splt) {
    // write unnormalized partial: O~ fp16 + m,l fp32
    char* pbase = wsp + (long)bx * PSTRIDE;
    #pragma unroll
    for (int qb = 0; qb < 4; ++qb)
      #pragma unroll
      for (int r = 0; r < 4; ++r) {
        const int q = qb * 16 + gq * 4 + r;
        #pragma unroll
        for (int cb = 0; cb < 4; ++cb) {
          const int c = w * 64 + cb * 16 + lp;
          *(ushort*)(pbase + (q * 256 + c) * 2) = hbits(acc[qb][cb][r]);
        }
      }
    if (lane < 16) {
      const int q = w * 16 + lp;
      *(float*)(pbase + 32768 + q * 4) = mrun;
      *(float*)(pbase + 33024 + q * 4) = lsum;
    }
  } else {
    if (lane < 16) Llds[w * 16 + lp] = lsum;
    __syncthreads();
    float* ob = out + (long)bn * NQ * Cc;
    #pragma unroll
    for (int qb = 0; qb < 4; ++qb) {
      f32x4 lv = *(const f32x4*)&Llds[qb * 16 + gq * 4];
      #pragma unroll
      for (int r = 0; r < 4; ++r) {
        const float iv = 1.0f / lv[r];
        const int q = qb * 16 + gq * 4 + r;
        #pragma unroll
        for (int cb = 0; cb < 4; ++cb) {
          const int c = w * 64 + cb * 16 + lp;
          ob[q * Cc + c] = acc[qb][cb][r] * iv;
        }
      }
    }
  }
}

// combine the two L-half partials of each cell:
// O = (a0*O~0 + a1*O~1) / (a0*l0 + a1*l1),  a_h = exp(m_h - max(m0,m1))
__global__ __launch_bounds__(256) void combine_halves(
    const char* __restrict__ ws, float* __restrict__ out)
{
  const int cell = blockIdx.x >> 1;
  const int qh   = blockIdx.x & 1;      // q-half 0..1 (32 rows each)
  const int t    = threadIdx.x;

  const char* p0 = ws + (long)(cell * 2 + 0) * PSTRIDE;
  const char* p1 = ws + (long)(cell * 2 + 1) * PSTRIDE;
  float* ob = out + (long)cell * (NQ * Cc);

  #pragma unroll
  for (int v = 0; v < 4; ++v) {
    const int f = qh * 8192 + v * 2048 + t * 8;   // flat elem in [64][256]
    const int q = f >> 8;
    const float m0 = *(const float*)(p0 + 32768 + q * 4);
    const float m1 = *(const float*)(p1 + 32768 + q * 4);
    const float l0 = *(const float*)(p0 + 33024 + q * 4);
    const float l1 = *(const float*)(p1 + 33024 + q * 4);
    const float M  = fmaxf(m0, m1);
    const float a0 = __expf(m0 - M), a1 = __expf(m1 - M);
    const float inv = 1.0f / (a0 * l0 + a1 * l1);

    half8 x0 = *(const half8*)(p0 + (long)f * 2);
    half8 x1 = *(const half8*)(p1 + (long)f * 2);
    float* o = ob + f;
    #pragma unroll
    for (int j = 0; j < 8; ++j)
      o[j] = (a0 * (float)x0[j] + a1 * (float)x1[j]) * inv;
  }
}

extern "C" void kernel_launch(void* const* d_in, const int* in_sizes, int n_in,
                              void* d_out, int out_size, void* d_ws, size_t ws_size,
                              hipStream_t stream) {
  const float* img = (const float*)d_in[0];
  const float* qry = (const float*)d_in[1];
  float* outp      = (float*)d_out;
  if (ws_size >= (size_t)WS_NEED) {
    attn_cells<<<dim3(Bc * 49 * 2), dim3(256), 0, stream>>>(img, qry, outp, (char*)d_ws, 1);
    combine_halves<<<dim3(Bc * 49 * 2), dim3(256), 0, stream>>>((const char*)d_ws, outp);
  } else {
    attn_cells<<<dim3(Bc * 49), dim3(256), 0, stream>>>(img, qry, outp, (char*)d_ws, 0);
  }
}

// Round 8
// 107.572 us; speedup vs baseline: 1.3852x; 1.3852x over previous
//
#include <hip/hip_runtime.h>

typedef _Float16 half8 __attribute__((ext_vector_type(8)));
typedef _Float16 half4 __attribute__((ext_vector_type(4)));
typedef __fp16   fp16x2 __attribute__((ext_vector_type(2)));
typedef float f32x4  __attribute__((ext_vector_type(4)));

#define DEVI __device__ __forceinline__

// problem constants (B,H,W,C fixed by the reference)
constexpr int Bc = 8;
constexpr int Hc = 224;
constexpr int Wc = 224;
constexpr int Cc = 256;
constexpr int NQ = 64;
constexpr int TS = 32;        // cell tile side (224/7)
constexpr int Lc = TS * TS;   // 1024 positions per cell
constexpr int KL = 64;        // l-chunk
constexpr int NT = Lc / KL;   // 16 chunks per full cell

constexpr int NFULL  = 256;                 // cells 0..255: one full block each
constexpr int NSPLIT = 392 - NFULL;         // cells 256..391: two half blocks
constexpr int NHALF  = NSPLIT * 2;          // 272 half blocks

// split-L partial layout in d_ws: per half-block slot:
//   [64][256] fp16 O~ (unnormalized, rel. local max)  = 32768 B
//   [64] f32 m                                        =   256 B
//   [64] f32 l                                        =   256 B
constexpr long PSTRIDE = 64 * 256 * 2 + 64 * 4 + 64 * 4;   // 33280
constexpr long WS_NEED = (long)NHALF * PSTRIDE;            // ~9.05 MB

// fp16-element index inside a 64x256 chunk, subtiled [l/4][c/16][4][16]
DEVI int subidx(int l, int c) {
  return ((((l >> 2) << 4) | (c >> 4)) << 6) | (((l & 3) << 4) | (c & 15));
}

// LDS byte offset of a shared-memory pointer (generic -> AS(3) addrspacecast)
DEVI uint ldsoff(const void* p) {
  return (uint)(uintptr_t)(const __attribute__((address_space(3))) char*)p;
}

union PKU { fp16x2 h; uint u; };
DEVI uint pkrtz(float a, float b) { PKU x; x.h = __builtin_amdgcn_cvt_pkrtz(a, b); return x.u; }
union HBU { _Float16 h; ushort u; };
DEVI ushort hbits(float x) { HBU v; v.h = (_Float16)x; return v.u; }

__global__ __launch_bounds__(256, 2) void attn_cells(
    const float* __restrict__ img,   // fp32 [B,224,224,256]
    const float* __restrict__ qry,   // fp32 [64,256]
    float* __restrict__ out,         // fp32 [B,49,64,256]
    char* __restrict__ wsp,          // partials (half blocks)
    int splt)
{
  __shared__ _Float16 Rlds[2][KL * Cc]; // 2 x 32KB, subtiled fp16
  __shared__ _Float16 Plds[4][16 * KL]; // per-wave P rows (fp16), swizzled
  __shared__ float    Slds[NQ];         // per-chunk rescale factors
  __shared__ float    Llds[NQ];         // final sum-exp

  const int tid  = threadIdx.x;
  const int w    = tid >> 6;          // wave 0..3
  const int lane = tid & 63;
  const int lp   = lane & 15;
  const int gq   = lane >> 4;         // 0..3

  const int bx = blockIdx.x;
  // LPT-mixed decode: blocks [0,NFULL) = full cells 0..255 (direct output);
  // blocks [NFULL, NFULL+NHALF) = half s of split cell 256 + s/2.
  int bn, tbeg, tend, pslot;
  if (splt && bx >= NFULL) {
    const int s = bx - NFULL;         // 0..271
    bn    = NFULL + (s >> 1);
    tbeg  = (s & 1) * (NT / 2);
    tend  = tbeg + NT / 2;
    pslot = s;
  } else {
    bn    = bx;
    tbeg  = 0;
    tend  = NT;
    pslot = -1;
  }

  const int b  = bn / 49;
  const int n  = bn % 49;
  const int i0 = n / 7, j0 = n % 7;

  const long cellbase = (((long)b * Hc + i0 * TS) * Wc + j0 * TS) * Cc;

  // staging decode: 8 granules of 8 elements per thread; granule G covers
  // chunk elements [8G, 8G+8) == R[l][c..c+7] in the subtiled layout
  int goff[8], lds_off[8];
  #pragma unroll
  for (int s = 0; s < 8; ++s) {
    int G   = s * 256 + tid;                       // 0..2047
    int blk = G >> 3, sub = G & 7;
    int l   = ((blk >> 4) << 2) | ((sub >> 1) & 3);
    int c   = ((blk & 15) << 4) | ((sub & 1) << 3);
    int y   = l >> 5, x = l & 31;
    goff[s]    = (y * Wc + x) * Cc + c;            // + t*2*Wc*Cc per chunk
    lds_off[s] = G << 3;                           // fp16 elements
  }

  // Q fragments (B-operand of S^T = R.Q^T), RNE convert (one-time)
  half8 bq[8];
  {
    const int qrow = (w << 4) | lp;
    #pragma unroll
    for (int kc = 0; kc < 8; ++kc) {
      const float* qp = &qry[qrow * Cc + kc * 32 + gq * 8];
      f32x4 lo = *(const f32x4*)qp;
      f32x4 hi = *(const f32x4*)(qp + 4);
      half8 hh;
      #pragma unroll
      for (int j = 0; j < 4; ++j) { hh[j] = (_Float16)lo[j]; hh[j + 4] = (_Float16)hi[j]; }
      bq[kc] = hh;
    }
  }

  f32x4 acc[4][4];
  #pragma unroll
  for (int qb = 0; qb < 4; ++qb)
    #pragma unroll
    for (int cb = 0; cb < 4; ++cb) acc[qb][cb] = f32x4{0.f, 0.f, 0.f, 0.f};

  float mrun = -3.0e38f;
  float lsum = 0.0f;

  // prologue: stage chunk tbeg (tbeg even -> buffer 0)
  {
    const float* gb = img + cellbase + (long)tbeg * (2 * Wc * Cc);
    #pragma unroll
    for (int s = 0; s < 8; ++s) {
      f32x4 lo = *(const f32x4*)&gb[goff[s]];
      f32x4 hi = *(const f32x4*)&gb[goff[s] + 4];
      uint4 pk;
      pk.x = pkrtz(lo[0], lo[1]); pk.y = pkrtz(lo[2], lo[3]);
      pk.z = pkrtz(hi[0], hi[1]); pk.w = pkrtz(hi[2], hi[3]);
      *(uint4*)&Rlds[0][lds_off[s]] = pk;
    }
  }
  __syncthreads();

  // per-lane base for PV tr-reads: lane (gq,lp) reads 4 contiguous fp16 at
  // R[l0 + (lp>>2)][c0 + 4*(lp&3)]; HW permutation delivers
  // out[j] = R[l0+j][c0+lp].  l0 = kc*32+gq*8+u*4, c0 = w*64+cb*16.
  const uint trlane = (uint)(gq * 4096 + w * 512 +
                             ((((lp >> 2) << 4) | ((lp & 3) << 2)) << 1));

  for (int t = tbeg; t < tend; ++t) {
    const int pb = t & 1;
    const _Float16* Rbuf = &Rlds[pb][0];
    const uint trbase = ldsoff(Rbuf) + trlane;

    if (t + 1 < tend) {   // stage next chunk into the free buffer
      const float* gb = img + cellbase + (long)(t + 1) * (2 * Wc * Cc);
      _Float16* Rn = &Rlds[pb ^ 1][0];
      #pragma unroll
      for (int s = 0; s < 8; ++s) {
        f32x4 lo = *(const f32x4*)&gb[goff[s]];
        f32x4 hi = *(const f32x4*)&gb[goff[s] + 4];
        uint4 pk;
        pk.x = pkrtz(lo[0], lo[1]); pk.y = pkrtz(lo[2], lo[3]);
        pk.z = pkrtz(hi[0], hi[1]); pk.w = pkrtz(hi[2], hi[3]);
        *(uint4*)&Rn[lds_off[s]] = pk;
      }
    }

    // ---- S^T = R . Q^T  (wave handles q rows 16w..16w+15) ----
    f32x4 sv[4];
    #pragma unroll
    for (int lb = 0; lb < 4; ++lb) sv[lb] = f32x4{0.f, 0.f, 0.f, 0.f};
    #pragma unroll
    for (int kc = 0; kc < 8; ++kc) {
      #pragma unroll
      for (int lb = 0; lb < 4; ++lb) {
        half8 a = *(const half8*)&Rbuf[subidx(lb * 16 + lp, kc * 32 + gq * 8)];
        sv[lb] = __builtin_amdgcn_mfma_f32_16x16x32_f16(a, bq[kc], sv[lb], 0, 0, 0);
      }
    }
    // lane holds S^T[l = 16lb+4gq+r][q = 16w+lp]

    // ---- online softmax for q = 16w+lp ----
    float cmax = sv[0][0];
    #pragma unroll
    for (int lb = 0; lb < 4; ++lb)
      #pragma unroll
      for (int r = 0; r < 4; ++r) cmax = fmaxf(cmax, sv[lb][r]);
    cmax = fmaxf(cmax, __shfl_xor(cmax, 16));
    cmax = fmaxf(cmax, __shfl_xor(cmax, 32));

    float mnew  = fmaxf(mrun, cmax);
    float scale = __expf(mrun - mnew);

    float ps = 0.0f;
    float pv[4][4];
    #pragma unroll
    for (int lb = 0; lb < 4; ++lb)
      #pragma unroll
      for (int r = 0; r < 4; ++r) {
        float p = __expf(sv[lb][r] - mnew);
        pv[lb][r] = p; ps += p;
      }
    ps += __shfl_xor(ps, 16);
    ps += __shfl_xor(ps, 32);
    lsum = lsum * scale + ps;
    mrun = mnew;

    // write P rows (fp16) to per-wave swizzled LDS
    {
      char* Pw = (char*)&Plds[w][0];
      #pragma unroll
      for (int lb = 0; lb < 4; ++lb) {
        uint lo = pkrtz(pv[lb][0], pv[lb][1]);
        uint hi = pkrtz(pv[lb][2], pv[lb][3]);
        int base = lp * 128 + lb * 32 + gq * 8;   // l = 16lb + 4gq
        int swz  = (lp & 7) << 4;
        *(uint*)(Pw + ((base ^ swz)))     = lo;
        *(uint*)(Pw + ((base ^ swz) + 4)) = hi;
      }
      if (lane < 16) Slds[w * 16 + lp] = scale;
    }

    __syncthreads();   // P + scale visible to all waves

    // ---- PV: wave computes O[all 64 q][c slice 64w..64w+64) ----
    #pragma unroll
    for (int qb = 0; qb < 4; ++qb) {
      f32x4 sc = *(const f32x4*)&Slds[qb * 16 + gq * 4];
      #pragma unroll
      for (int cb = 0; cb < 4; ++cb) acc[qb][cb] *= sc;
    }

    #pragma unroll
    for (int kc = 0; kc < 2; ++kc) {
      half8 pa[4];
      #pragma unroll
      for (int qb = 0; qb < 4; ++qb) {
        const char* Pr = (const char*)&Plds[qb][0];
        int off = (lp * 128 + gq * 16 + kc * 64) ^ ((lp & 7) << 4);
        pa[qb] = *(const half8*)(Pr + off);
      }
      // PV B-frags via hardware transpose read (T10)
      half4 tr[4][2];
      #pragma unroll
      for (int cb = 0; cb < 4; ++cb) {
        #pragma unroll
        for (int u = 0; u < 2; ++u) {
          asm volatile("ds_read_b64_tr_b16 %0, %1 offset:%2"
                       : "=v"(tr[cb][u])
                       : "v"(trbase), "i"(kc * 16384 + u * 2048 + cb * 128));
        }
      }
      asm volatile("s_waitcnt lgkmcnt(0)" ::: "memory");
      __builtin_amdgcn_sched_barrier(0);

      #pragma unroll
      for (int qb = 0; qb < 4; ++qb)
        #pragma unroll
        for (int cb = 0; cb < 4; ++cb) {
          half8 bv = __builtin_shufflevector(tr[cb][0], tr[cb][1], 0, 1, 2, 3, 4, 5, 6, 7);
          acc[qb][cb] = __builtin_amdgcn_mfma_f32_16x16x32_f16(pa[qb], bv, acc[qb][cb], 0, 0, 0);
        }
    }

    __syncthreads();   // frees R buffer and P region
  }

  // ---- epilogue ----
  if (pslot >= 0) {
    // write unnormalized partial: O~ fp16 + m,l fp32
    char* pbase = wsp + (long)pslot * PSTRIDE;
    #pragma unroll
    for (int qb = 0; qb < 4; ++qb)
      #pragma unroll
      for (int r = 0; r < 4; ++r) {
        const int q = qb * 16 + gq * 4 + r;
        #pragma unroll
        for (int cb = 0; cb < 4; ++cb) {
          const int c = w * 64 + cb * 16 + lp;
          *(ushort*)(pbase + (q * 256 + c) * 2) = hbits(acc[qb][cb][r]);
        }
      }
    if (lane < 16) {
      const int q = w * 16 + lp;
      *(float*)(pbase + 32768 + q * 4) = mrun;
      *(float*)(pbase + 33024 + q * 4) = lsum;
    }
  } else {
    if (lane < 16) Llds[w * 16 + lp] = lsum;
    __syncthreads();
    float* ob = out + (long)bn * NQ * Cc;
    #pragma unroll
    for (int qb = 0; qb < 4; ++qb) {
      f32x4 lv = *(const f32x4*)&Llds[qb * 16 + gq * 4];
      #pragma unroll
      for (int r = 0; r < 4; ++r) {
        const float iv = 1.0f / lv[r];
        const int q = qb * 16 + gq * 4 + r;
        #pragma unroll
        for (int cb = 0; cb < 4; ++cb) {
          const int c = w * 64 + cb * 16 + lp;
          ob[q * Cc + c] = acc[qb][cb][r] * iv;
        }
      }
    }
  }
}

// combine the two L-half partials of each split cell:
// O = (a0*O~0 + a1*O~1) / (a0*l0 + a1*l1),  a_h = exp(m_h - max(m0,m1))
__global__ __launch_bounds__(256) void combine_halves(
    const char* __restrict__ ws, float* __restrict__ out)
{
  const int s    = blockIdx.x;          // 0..2*NSPLIT-1
  const int ci   = s >> 1;              // split-cell index 0..NSPLIT-1
  const int cell = NFULL + ci;
  const int qh   = s & 1;               // q-half 0..1 (32 rows each)
  const int t    = threadIdx.x;

  const char* p0 = ws + (long)(ci * 2 + 0) * PSTRIDE;
  const char* p1 = ws + (long)(ci * 2 + 1) * PSTRIDE;
  float* ob = out + (long)cell * (NQ * Cc);

  #pragma unroll
  for (int v = 0; v < 4; ++v) {
    const int f = qh * 8192 + v * 2048 + t * 8;   // flat elem in [64][256]
    const int q = f >> 8;
    const float m0 = *(const float*)(p0 + 32768 + q * 4);
    const float m1 = *(const float*)(p1 + 32768 + q * 4);
    const float l0 = *(const float*)(p0 + 33024 + q * 4);
    const float l1 = *(const float*)(p1 + 33024 + q * 4);
    const float M  = fmaxf(m0, m1);
    const float a0 = __expf(m0 - M), a1 = __expf(m1 - M);
    const float inv = 1.0f / (a0 * l0 + a1 * l1);

    half8 x0 = *(const half8*)(p0 + (long)f * 2);
    half8 x1 = *(const half8*)(p1 + (long)f * 2);
    float* o = ob + f;
    #pragma unroll
    for (int j = 0; j < 8; ++j)
      o[j] = (a0 * (float)x0[j] + a1 * (float)x1[j]) * inv;
  }
}

extern "C" void kernel_launch(void* const* d_in, const int* in_sizes, int n_in,
                              void* d_out, int out_size, void* d_ws, size_t ws_size,
                              hipStream_t stream) {
  const float* img = (const float*)d_in[0];
  const float* qry = (const float*)d_in[1];
  float* outp      = (float*)d_out;
  if (ws_size >= (size_t)WS_NEED) {
    attn_cells<<<dim3(NFULL + NHALF), dim3(256), 0, stream>>>(img, qry, outp, (char*)d_ws, 1);
    combine_halves<<<dim3(NHALF), dim3(256), 0, stream>>>((const char*)d_ws, outp);
  } else {
    attn_cells<<<dim3(Bc * 49), dim3(256), 0, stream>>>(img, qry, outp, (char*)d_ws, 0);
  }
}

// Round 9
// 97.361 us; speedup vs baseline: 1.5305x; 1.1049x over previous
//
#include <hip/hip_runtime.h>

typedef _Float16 half8 __attribute__((ext_vector_type(8)));
typedef _Float16 half4 __attribute__((ext_vector_type(4)));
typedef __fp16   fp16x2 __attribute__((ext_vector_type(2)));
typedef float f32x4  __attribute__((ext_vector_type(4)));

#define DEVI __device__ __forceinline__

// problem constants (B,H,W,C fixed by the reference)
constexpr int Bc = 8;
constexpr int Hc = 224;
constexpr int Wc = 224;
constexpr int Cc = 256;
constexpr int NQ = 64;
constexpr int TS = 32;        // cell tile side (224/7)
constexpr int Lc = TS * TS;   // 1024 positions per cell
constexpr int KL = 64;        // l-chunk
constexpr int NT = Lc / KL;   // 16 chunks per cell

// fp16-element index inside a 64x256 chunk, subtiled [l/4][c/16][4][16]
DEVI int subidx(int l, int c) {
  return ((((l >> 2) << 4) | (c >> 4)) << 6) | (((l & 3) << 4) | (c & 15));
}

// LDS byte offset of a shared-memory pointer (generic -> AS(3) addrspacecast)
DEVI uint ldsoff(const void* p) {
  return (uint)(uintptr_t)(const __attribute__((address_space(3))) char*)p;
}

union PKU { fp16x2 h; uint u; };
DEVI uint pkrtz(float a, float b) { PKU x; x.h = __builtin_amdgcn_cvt_pkrtz(a, b); return x.u; }

__global__ __launch_bounds__(256, 2) void attn_cells(
    const float* __restrict__ img,   // fp32 [B,224,224,256]
    const float* __restrict__ qry,   // fp32 [64,256]
    float* __restrict__ out)         // fp32 [B,49,64,256]
{
  __shared__ _Float16 Rlds[2][KL * Cc]; // 2 x 32KB, subtiled fp16
  __shared__ _Float16 Plds[4][16 * KL]; // per-wave P rows (fp16), swizzled
  __shared__ float    Slds[NQ];         // per-chunk rescale factors
  __shared__ float    Llds[NQ];         // final sum-exp

  const int tid  = threadIdx.x;
  const int w    = tid >> 6;          // wave 0..3
  const int lane = tid & 63;
  const int lp   = lane & 15;
  const int gq   = lane >> 4;         // 0..3

  const int bn = blockIdx.x;          // cell id: b*49 + (i*7+j)
  const int b  = bn / 49;
  const int n  = bn % 49;
  const int i0 = n / 7, j0 = n % 7;

  const long cellbase = (((long)b * Hc + i0 * TS) * Wc + j0 * TS) * Cc;

  // staging decode: 8 granules of 8 elements per thread; granule G covers
  // chunk elements [8G, 8G+8) == R[l][c..c+7] in the subtiled layout
  int lds_off[8];
  uint voffb[8];                      // per-lane BYTE offset within a chunk
  #pragma unroll
  for (int s = 0; s < 8; ++s) {
    int G   = s * 256 + tid;                       // 0..2047
    int blk = G >> 3, sub = G & 7;
    int l   = ((blk >> 4) << 2) | ((sub >> 1) & 3);
    int c   = ((blk & 15) << 4) | ((sub & 1) << 3);
    int y   = l >> 5, x = l & 31;
    voffb[s]   = (uint)(((y * Wc + x) * Cc + c) * 4);
    lds_off[s] = G << 3;                           // fp16 elements
  }

  // Q fragments (B-operand of S^T = R.Q^T), RNE convert (one-time)
  half8 bq[8];
  {
    const int qrow = (w << 4) | lp;
    #pragma unroll
    for (int kc = 0; kc < 8; ++kc) {
      const float* qp = &qry[qrow * Cc + kc * 32 + gq * 8];
      f32x4 lo = *(const f32x4*)qp;
      f32x4 hi = *(const f32x4*)(qp + 4);
      half8 hh;
      #pragma unroll
      for (int j = 0; j < 4; ++j) { hh[j] = (_Float16)lo[j]; hh[j + 4] = (_Float16)hi[j]; }
      bq[kc] = hh;
    }
  }

  f32x4 acc[4][4];
  #pragma unroll
  for (int qb = 0; qb < 4; ++qb)
    #pragma unroll
    for (int cb = 0; cb < 4; ++cb) acc[qb][cb] = f32x4{0.f, 0.f, 0.f, 0.f};

  float mrun = -3.0e38f;
  float lsum = 0.0f;

  // prologue: stage chunk 0 (fp32 -> fp16 pkrtz)
  {
    const float* gb = img + cellbase;
    #pragma unroll
    for (int s = 0; s < 8; ++s) {
      const float* p = (const float*)((const char*)gb + voffb[s]);
      f32x4 lo = *(const f32x4*)p;
      f32x4 hi = *(const f32x4*)(p + 4);
      uint4 pk;
      pk.x = pkrtz(lo[0], lo[1]); pk.y = pkrtz(lo[2], lo[3]);
      pk.z = pkrtz(hi[0], hi[1]); pk.w = pkrtz(hi[2], hi[3]);
      *(uint4*)&Rlds[0][lds_off[s]] = pk;
    }
  }
  __syncthreads();

  // per-lane base for PV tr-reads: lane (gq,lp) reads 4 contiguous fp16 at
  // R[l0 + (lp>>2)][c0 + 4*(lp&3)]; HW permutation delivers
  // out[j] = R[l0+j][c0+lp].  l0 = kc*32+gq*8+u*4, c0 = w*64+cb*16.
  const uint trlane = (uint)(gq * 4096 + w * 512 +
                             ((((lp >> 2) << 4) | ((lp & 3) << 2)) << 1));

  for (int t = 0; t < NT; ++t) {
    const int pb = t & 1;
    const _Float16* Rbuf = &Rlds[pb][0];
    const uint trbase = ldsoff(Rbuf) + trlane;

    // ---- forced-async stage: ISSUE chunk t+1 loads NOW (inline asm pins
    //      the issue point; results land in VGPRs, drained after PV) ----
    f32x4 stg[16];
    if (t + 1 < NT) {
      const float* gb = img + cellbase + (long)(t + 1) * (2 * Wc * Cc); // uniform -> SGPR base
      #pragma unroll
      for (int s = 0; s < 8; ++s) {
        asm volatile("global_load_dwordx4 %0, %1, %2"
                     : "=&v"(stg[2 * s])
                     : "v"(voffb[s]), "s"(gb));
        asm volatile("global_load_dwordx4 %0, %1, %2 offset:16"
                     : "=&v"(stg[2 * s + 1])
                     : "v"(voffb[s]), "s"(gb));
      }
    }

    // ---- S^T = R . Q^T  (wave handles q rows 16w..16w+15) ----
    f32x4 sv[4];
    #pragma unroll
    for (int lb = 0; lb < 4; ++lb) sv[lb] = f32x4{0.f, 0.f, 0.f, 0.f};
    #pragma unroll
    for (int kc = 0; kc < 8; ++kc) {
      #pragma unroll
      for (int lb = 0; lb < 4; ++lb) {
        half8 a = *(const half8*)&Rbuf[subidx(lb * 16 + lp, kc * 32 + gq * 8)];
        sv[lb] = __builtin_amdgcn_mfma_f32_16x16x32_f16(a, bq[kc], sv[lb], 0, 0, 0);
      }
    }
    // lane holds S^T[l = 16lb+4gq+r][q = 16w+lp]

    // ---- online softmax for q = 16w+lp ----
    float cmax = sv[0][0];
    #pragma unroll
    for (int lb = 0; lb < 4; ++lb)
      #pragma unroll
      for (int r = 0; r < 4; ++r) cmax = fmaxf(cmax, sv[lb][r]);
    cmax = fmaxf(cmax, __shfl_xor(cmax, 16));
    cmax = fmaxf(cmax, __shfl_xor(cmax, 32));

    float mnew  = fmaxf(mrun, cmax);
    float scale = __expf(mrun - mnew);

    float ps = 0.0f;
    float pv[4][4];
    #pragma unroll
    for (int lb = 0; lb < 4; ++lb)
      #pragma unroll
      for (int r = 0; r < 4; ++r) {
        float p = __expf(sv[lb][r] - mnew);
        pv[lb][r] = p; ps += p;
      }
    ps += __shfl_xor(ps, 16);
    ps += __shfl_xor(ps, 32);
    lsum = lsum * scale + ps;
    mrun = mnew;

    // write P rows (fp16) to per-wave swizzled LDS
    {
      char* Pw = (char*)&Plds[w][0];
      #pragma unroll
      for (int lb = 0; lb < 4; ++lb) {
        uint lo = pkrtz(pv[lb][0], pv[lb][1]);
        uint hi = pkrtz(pv[lb][2], pv[lb][3]);
        int base = lp * 128 + lb * 32 + gq * 8;   // l = 16lb + 4gq
        int swz  = (lp & 7) << 4;
        *(uint*)(Pw + ((base ^ swz)))     = lo;
        *(uint*)(Pw + ((base ^ swz) + 4)) = hi;
      }
      if (lane < 16) Slds[w * 16 + lp] = scale;
    }

    __syncthreads();   // P + scale visible to all waves

    // ---- PV: wave computes O[all 64 q][c slice 64w..64w+64) ----
    #pragma unroll
    for (int qb = 0; qb < 4; ++qb) {
      f32x4 sc = *(const f32x4*)&Slds[qb * 16 + gq * 4];
      #pragma unroll
      for (int cb = 0; cb < 4; ++cb) acc[qb][cb] *= sc;
    }

    #pragma unroll
    for (int kc = 0; kc < 2; ++kc) {
      half8 pa[4];
      #pragma unroll
      for (int qb = 0; qb < 4; ++qb) {
        const char* Pr = (const char*)&Plds[qb][0];
        int off = (lp * 128 + gq * 16 + kc * 64) ^ ((lp & 7) << 4);
        pa[qb] = *(const half8*)(Pr + off);
      }
      // PV B-frags via hardware transpose read (T10)
      half4 tr[4][2];
      #pragma unroll
      for (int cb = 0; cb < 4; ++cb) {
        #pragma unroll
        for (int u = 0; u < 2; ++u) {
          asm volatile("ds_read_b64_tr_b16 %0, %1 offset:%2"
                       : "=v"(tr[cb][u])
                       : "v"(trbase), "i"(kc * 16384 + u * 2048 + cb * 128));
        }
      }
      asm volatile("s_waitcnt lgkmcnt(0)" ::: "memory");
      __builtin_amdgcn_sched_barrier(0);

      #pragma unroll
      for (int qb = 0; qb < 4; ++qb)
        #pragma unroll
        for (int cb = 0; cb < 4; ++cb) {
          half8 bv = __builtin_shufflevector(tr[cb][0], tr[cb][1], 0, 1, 2, 3, 4, 5, 6, 7);
          acc[qb][cb] = __builtin_amdgcn_mfma_f32_16x16x32_f16(pa[qb], bv, acc[qb][cb], 0, 0, 0);
        }
    }

    // ---- drain forced-async loads, convert, ds_write into free buffer ----
    if (t + 1 < NT) {
      asm volatile("s_waitcnt vmcnt(0)" ::: "memory");
      __builtin_amdgcn_sched_barrier(0);
      _Float16* Rn = &Rlds[pb ^ 1][0];
      #pragma unroll
      for (int s = 0; s < 8; ++s) {
        uint4 pk;
        pk.x = pkrtz(stg[2 * s][0], stg[2 * s][1]);
        pk.y = pkrtz(stg[2 * s][2], stg[2 * s][3]);
        pk.z = pkrtz(stg[2 * s + 1][0], stg[2 * s + 1][1]);
        pk.w = pkrtz(stg[2 * s + 1][2], stg[2 * s + 1][3]);
        *(uint4*)&Rn[lds_off[s]] = pk;
      }
    }

    __syncthreads();   // stage visible; frees P region; R[pb] reads done
  }

  // ---- epilogue: divide by sum-exp, write fp32 ----
  if (lane < 16) Llds[w * 16 + lp] = lsum;
  __syncthreads();

  float* ob = out + (long)bn * NQ * Cc;
  #pragma unroll
  for (int qb = 0; qb < 4; ++qb) {
    f32x4 lv = *(const f32x4*)&Llds[qb * 16 + gq * 4];
    #pragma unroll
    for (int r = 0; r < 4; ++r) {
      const float iv = 1.0f / lv[r];
      const int q = qb * 16 + gq * 4 + r;
      #pragma unroll
      for (int cb = 0; cb < 4; ++cb) {
        const int c = w * 64 + cb * 16 + lp;
        ob[q * Cc + c] = acc[qb][cb][r] * iv;
      }
    }
  }
}

extern "C" void kernel_launch(void* const* d_in, const int* in_sizes, int n_in,
                              void* d_out, int out_size, void* d_ws, size_t ws_size,
                              hipStream_t stream) {
  const float* img = (const float*)d_in[0];
  const float* qry = (const float*)d_in[1];
  float* outp      = (float*)d_out;
  attn_cells<<<dim3(Bc * 49), dim3(256), 0, stream>>>(img, qry, outp);
}

// Round 10
// 95.004 us; speedup vs baseline: 1.5684x; 1.0248x over previous
//
#include <hip/hip_runtime.h>

typedef _Float16 half8 __attribute__((ext_vector_type(8)));
typedef _Float16 half4 __attribute__((ext_vector_type(4)));
typedef __fp16   fp16x2 __attribute__((ext_vector_type(2)));
typedef float f32x4  __attribute__((ext_vector_type(4)));

#define DEVI __device__ __forceinline__

// problem constants (B,H,W,C fixed by the reference)
constexpr int Bc = 8;
constexpr int Hc = 224;
constexpr int Wc = 224;
constexpr int Cc = 256;
constexpr int NQ = 64;
constexpr int TS = 32;        // cell tile side (224/7)
constexpr int Lc = TS * TS;   // 1024 positions per cell
constexpr int KL = 64;        // l-chunk
constexpr int NT = Lc / KL;   // 16 chunks

// fp16-element index inside a 64x256 chunk, subtiled [l/4][c/16][4][16]
DEVI int subidx(int l, int c) {
  return ((((l >> 2) << 4) | (c >> 4)) << 6) | (((l & 3) << 4) | (c & 15));
}

// LDS byte offset of a shared-memory pointer (generic -> AS(3) addrspacecast)
DEVI uint ldsoff(const void* p) {
  return (uint)(uintptr_t)(const __attribute__((address_space(3))) char*)p;
}

union PKU { fp16x2 h; uint u; };
DEVI uint pkrtz(float a, float b) { PKU x; x.h = __builtin_amdgcn_cvt_pkrtz(a, b); return x.u; }

__global__ __launch_bounds__(256, 2) void attn_cells(
    const float* __restrict__ img,   // fp32 [B,224,224,256]
    const float* __restrict__ qry,   // fp32 [64,256]
    float* __restrict__ out)         // fp32 [B,49,64,256]
{
  __shared__ _Float16 Rlds[2][KL * Cc]; // 2 x 32KB, subtiled fp16
  __shared__ _Float16 Plds[4][16 * KL]; // per-wave P rows (fp16), swizzled
  __shared__ float    Slds[NQ];         // per-chunk rescale factors
  __shared__ float    Llds[NQ];         // final sum-exp

  const int tid  = threadIdx.x;
  const int w    = tid >> 6;          // wave 0..3
  const int lane = tid & 63;
  const int lp   = lane & 15;
  const int gq   = lane >> 4;         // 0..3

  const int bn = blockIdx.x;          // cell id: b*49 + (i*7+j)
  const int b  = bn / 49;
  const int n  = bn % 49;
  const int i0 = n / 7, j0 = n % 7;

  const long cellbase = (((long)b * Hc + i0 * TS) * Wc + j0 * TS) * Cc;

  // staging decode: 8 granules of 8 elements per thread; granule G covers
  // chunk elements [8G, 8G+8) == R[l][c..c+7] in the subtiled layout
  int goff[8], lds_off[8];
  #pragma unroll
  for (int s = 0; s < 8; ++s) {
    int G   = s * 256 + tid;                       // 0..2047
    int blk = G >> 3, sub = G & 7;
    int l   = ((blk >> 4) << 2) | ((sub >> 1) & 3);
    int c   = ((blk & 15) << 4) | ((sub & 1) << 3);
    int y   = l >> 5, x = l & 31;
    goff[s]    = (y * Wc + x) * Cc + c;            // + t*2*Wc*Cc per chunk
    lds_off[s] = G << 3;                           // fp16 elements
  }

  // Q fragments (B-operand of S^T = R.Q^T), RNE convert (one-time)
  half8 bq[8];
  {
    const int qrow = (w << 4) | lp;
    #pragma unroll
    for (int kc = 0; kc < 8; ++kc) {
      const float* qp = &qry[qrow * Cc + kc * 32 + gq * 8];
      f32x4 lo = *(const f32x4*)qp;
      f32x4 hi = *(const f32x4*)(qp + 4);
      half8 h;
      #pragma unroll
      for (int j = 0; j < 4; ++j) { h[j] = (_Float16)lo[j]; h[j + 4] = (_Float16)hi[j]; }
      bq[kc] = h;
    }
  }

  f32x4 acc[4][4];
  #pragma unroll
  for (int qb = 0; qb < 4; ++qb)
    #pragma unroll
    for (int cb = 0; cb < 4; ++cb) acc[qb][cb] = f32x4{0.f, 0.f, 0.f, 0.f};

  float mrun = -3.0e38f;
  float lsum = 0.0f;

  // prologue: stage chunk 0 (fp32 -> fp16 pkrtz)
  {
    const float* gb = img + cellbase;
    #pragma unroll
    for (int s = 0; s < 8; ++s) {
      f32x4 lo = *(const f32x4*)&gb[goff[s]];
      f32x4 hi = *(const f32x4*)&gb[goff[s] + 4];
      uint4 pk;
      pk.x = pkrtz(lo[0], lo[1]); pk.y = pkrtz(lo[2], lo[3]);
      pk.z = pkrtz(hi[0], hi[1]); pk.w = pkrtz(hi[2], hi[3]);
      *(uint4*)&Rlds[0][lds_off[s]] = pk;
    }
  }
  __syncthreads();

  // per-lane base for PV tr-reads: lane (gq,lp) reads 4 contiguous fp16 at
  // R[l0 + (lp>>2)][c0 + 4*(lp&3)]; HW permutation delivers
  // out[j] = R[l0+j][c0+lp].  l0 = kc*32+gq*8+u*4, c0 = w*64+cb*16.
  const uint trlane = (uint)(gq * 4096 + w * 512 +
                             ((((lp >> 2) << 4) | ((lp & 3) << 2)) << 1));

  for (int t = 0; t < NT; ++t) {
    const int pb = t & 1;
    const _Float16* Rbuf = &Rlds[pb][0];
    const uint trbase = ldsoff(Rbuf) + trlane;

    if (t + 1 < NT) {   // stage next chunk into the free buffer
      const float* gb = img + cellbase + (long)(t + 1) * (2 * Wc * Cc);
      _Float16* Rn = &Rlds[pb ^ 1][0];
      #pragma unroll
      for (int s = 0; s < 8; ++s) {
        f32x4 lo = *(const f32x4*)&gb[goff[s]];
        f32x4 hi = *(const f32x4*)&gb[goff[s] + 4];
        uint4 pk;
        pk.x = pkrtz(lo[0], lo[1]); pk.y = pkrtz(lo[2], lo[3]);
        pk.z = pkrtz(hi[0], hi[1]); pk.w = pkrtz(hi[2], hi[3]);
        *(uint4*)&Rn[lds_off[s]] = pk;
      }
    }

    // ---- S^T = R . Q^T  (wave handles q rows 16w..16w+15) ----
    f32x4 sv[4];
    #pragma unroll
    for (int lb = 0; lb < 4; ++lb) sv[lb] = f32x4{0.f, 0.f, 0.f, 0.f};
    #pragma unroll
    for (int kc = 0; kc < 8; ++kc) {
      #pragma unroll
      for (int lb = 0; lb < 4; ++lb) {
        half8 a = *(const half8*)&Rbuf[subidx(lb * 16 + lp, kc * 32 + gq * 8)];
        sv[lb] = __builtin_amdgcn_mfma_f32_16x16x32_f16(a, bq[kc], sv[lb], 0, 0, 0);
      }
    }
    // lane holds S^T[l = 16lb+4gq+r][q = 16w+lp]

    // ---- online softmax for q = 16w+lp ----
    float cmax = sv[0][0];
    #pragma unroll
    for (int lb = 0; lb < 4; ++lb)
      #pragma unroll
      for (int r = 0; r < 4; ++r) cmax = fmaxf(cmax, sv[lb][r]);
    cmax = fmaxf(cmax, __shfl_xor(cmax, 16));
    cmax = fmaxf(cmax, __shfl_xor(cmax, 32));

    float mnew  = fmaxf(mrun, cmax);
    float scale = __expf(mrun - mnew);

    float ps = 0.0f;
    float pv[4][4];
    #pragma unroll
    for (int lb = 0; lb < 4; ++lb)
      #pragma unroll
      for (int r = 0; r < 4; ++r) {
        float p = __expf(sv[lb][r] - mnew);
        pv[lb][r] = p; ps += p;
      }
    ps += __shfl_xor(ps, 16);
    ps += __shfl_xor(ps, 32);
    lsum = lsum * scale + ps;
    mrun = mnew;

    // write P rows (fp16) to per-wave swizzled LDS
    {
      char* Pw = (char*)&Plds[w][0];
      #pragma unroll
      for (int lb = 0; lb < 4; ++lb) {
        uint lo = pkrtz(pv[lb][0], pv[lb][1]);
        uint hi = pkrtz(pv[lb][2], pv[lb][3]);
        int base = lp * 128 + lb * 32 + gq * 8;   // l = 16lb + 4gq
        int swz  = (lp & 7) << 4;
        *(uint*)(Pw + ((base ^ swz)))     = lo;
        *(uint*)(Pw + ((base ^ swz) + 4)) = hi;
      }
      if (lane < 16) Slds[w * 16 + lp] = scale;
    }

    __syncthreads();   // P + scale visible to all waves

    // ---- PV: wave computes O[all 64 q][c slice 64w..64w+64) ----
    #pragma unroll
    for (int qb = 0; qb < 4; ++qb) {
      f32x4 sc = *(const f32x4*)&Slds[qb * 16 + gq * 4];
      #pragma unroll
      for (int cb = 0; cb < 4; ++cb) acc[qb][cb] *= sc;
    }

    #pragma unroll
    for (int kc = 0; kc < 2; ++kc) {
      half8 pa[4];
      #pragma unroll
      for (int qb = 0; qb < 4; ++qb) {
        const char* Pr = (const char*)&Plds[qb][0];
        int off = (lp * 128 + gq * 16 + kc * 64) ^ ((lp & 7) << 4);
        pa[qb] = *(const half8*)(Pr + off);
      }
      // PV B-frags via hardware transpose read (T10)
      half4 tr[4][2];
      #pragma unroll
      for (int cb = 0; cb < 4; ++cb) {
        #pragma unroll
        for (int u = 0; u < 2; ++u) {
          asm volatile("ds_read_b64_tr_b16 %0, %1 offset:%2"
                       : "=v"(tr[cb][u])
                       : "v"(trbase), "i"(kc * 16384 + u * 2048 + cb * 128));
        }
      }
      asm volatile("s_waitcnt lgkmcnt(0)" ::: "memory");
      __builtin_amdgcn_sched_barrier(0);

      #pragma unroll
      for (int qb = 0; qb < 4; ++qb)
        #pragma unroll
        for (int cb = 0; cb < 4; ++cb) {
          half8 bv = __builtin_shufflevector(tr[cb][0], tr[cb][1], 0, 1, 2, 3, 4, 5, 6, 7);
          acc[qb][cb] = __builtin_amdgcn_mfma_f32_16x16x32_f16(pa[qb], bv, acc[qb][cb], 0, 0, 0);
        }
    }

    __syncthreads();   // frees R buffer (for stage t+2) and P region
  }

  // ---- epilogue: divide by sum-exp, write fp32 ----
  if (lane < 16) Llds[w * 16 + lp] = lsum;
  __syncthreads();

  float* ob = out + (long)bn * NQ * Cc;
  #pragma unroll
  for (int qb = 0; qb < 4; ++qb) {
    f32x4 lv = *(const f32x4*)&Llds[qb * 16 + gq * 4];
    #pragma unroll
    for (int r = 0; r < 4; ++r) {
      const float iv = 1.0f / lv[r];
      const int q = qb * 16 + gq * 4 + r;
      #pragma unroll
      for (int cb = 0; cb < 4; ++cb) {
        const int c = w * 64 + cb * 16 + lp;
        ob[q * Cc + c] = acc[qb][cb][r] * iv;
      }
    }
  }
}

extern "C" void kernel_launch(void* const* d_in, const int* in_sizes, int n_in,
                              void* d_out, int out_size, void* d_ws, size_t ws_size,
                              hipStream_t stream) {
  const float* img = (const float*)d_in[0];
  const float* qry = (const float*)d_in[1];
  float* outp      = (float*)d_out;
  dim3 grid(Bc * 49), block(256);
  attn_cells<<<grid, block, 0, stream>>>(img, qry, outp);
}